// Round 2
// baseline (162.688 us; speedup 1.0000x reference)
//
#include <hip/hip_runtime.h>

#define NPATH 60
#define KDIM  204
#define KPAD  224      // 7 k-chunks of 32, zero padded
#define NIJ   324
#define NTIL  21       // 21 n-tiles of 16 (324 -> 336)
#define HID   64

#define BHS   88       // Blds/Hlds row stride (u16): 176B = 11*16B aligned, 2-way banks (free)
#define CLS   232      // Clds row stride (u16): 464B = 29*16B aligned, 2-way banks (free)

typedef short bf16x8 __attribute__((ext_vector_type(8)));
typedef float f32x4  __attribute__((ext_vector_type(4)));

// One-time prepped operands in bf16 MFMA B-fragment order (module globals:
// graph-safe, rewritten by prep_kernel every call).
__device__ __align__(16) unsigned short g_w1s[4096];    // 2kc x 4nt x 64lane x 8
__device__ __align__(16) unsigned short g_w2s[4096];
__device__ __align__(16) unsigned short g_cgs[75264];   // 7kc x 21nt x 64lane x 8
__device__ unsigned char g_ptab[KDIM];
__device__ unsigned char g_ytab[KDIM];

// Proven RNE f32->bf16 (round-0 verified). Do NOT replace with
// v_cvt_pk_bf16_f32 asm: round-1 showed that path zeroes the pipeline
// (suspected swapped S0/S1 placement on gfx950 -- verify via disasm first).
__device__ inline unsigned short f2bf(float f) {
    unsigned int u = __builtin_bit_cast(unsigned int, f);
    u += 0x7fffu + ((u >> 16) & 1u);     // RNE
    return (unsigned short)(u >> 16);
}
__device__ inline float bf2f(unsigned short h) {
    unsigned int u = ((unsigned int)h) << 16;
    return __builtin_bit_cast(float, u);
}

__global__ void prep_kernel(const float* __restrict__ W1, const float* __restrict__ W2,
                            const float* __restrict__ cg, const float* __restrict__ rf,
                            const float* __restrict__ ylm)
{
    int idx = blockIdx.x * 256 + threadIdx.x;
    if (idx < 4096) {                                       // W1 -> fragment order
        int e = idx & 7, ln = (idx >> 3) & 63, nt = (idx >> 9) & 3, kc = idx >> 11;
        int k = kc * 32 + (ln >> 4) * 8 + e;
        int n = nt * 16 + (ln & 15);
        g_w1s[idx] = f2bf(W1[k * HID + n]);
    } else if (idx < 8192) {                                // W2 (n>=60 zero)
        int j = idx - 4096;
        int e = j & 7, ln = (j >> 3) & 63, nt = (j >> 9) & 3, kc = j >> 11;
        int k = kc * 32 + (ln >> 4) * 8 + e;
        int n = nt * 16 + (ln & 15);
        g_w2s[j] = f2bf(n < NPATH ? W2[k * NPATH + n] : 0.0f);
    } else if (idx < 8192 + 75264) {                        // cg (k>=204 / n>=324 zero)
        int j = idx - 8192;
        int e = j & 7, ln = (j >> 3) & 63;
        int nt = (j >> 9) % NTIL;
        int kc = j / (512 * NTIL);
        int k = kc * 32 + (ln >> 4) * 8 + e;
        int n = nt * 16 + (ln & 15);
        g_cgs[j] = f2bf((k < KDIM && n < NIJ) ? cg[k * NIJ + n] : 0.0f);
    } else if (idx < 8192 + 75264 + KDIM) {                 // gather tables
        int k = idx - (8192 + 75264);
        int p = 0, yy = 0;
        for (int q = 0; q < NPATH; q++) if (rf[k * NPATH + q] != 0.0f) p = q;
        for (int q = 0; q < 9; q++)     if (ylm[k * 9 + q]   != 0.0f) yy = q;
        g_ptab[k] = (unsigned char)p;
        g_ytab[k] = (unsigned char)yy;
    }
}

// Phase-overlapped LDS: Blds/Hlds dead before Clds is written.
union SmemU {
    struct {
        unsigned short Blds[64][BHS];   // radial basis, bf16   (11,264 B)
        unsigned short Hlds[64][BHS];   // hidden activations   (11,264 B)
    } p1;                               // 22,528 B
    unsigned short Clds[64][CLS];       // coeff bf16, k-pad 224 (29,696 B)
};

__global__ __launch_bounds__(256, 4) void fused_kernel(
    const float* __restrict__ r, const float* __restrict__ b1,
    const float* __restrict__ b2, float* __restrict__ out)
{
    __shared__ SmemU sm;
    __shared__ unsigned short Rl[64][61];   // R, bf16
    __shared__ float Yl[64][9];
    __shared__ unsigned char ptabL[KDIM];
    __shared__ unsigned char ytabL[KDIM];

    const int tid  = threadIdx.x;
    const int wv   = tid >> 6;
    const int lane = tid & 63;
    const int quad = lane >> 4;
    const int l16  = lane & 15;
    const int z0   = blockIdx.x * 64;

    // ---- Phase A (merged): tables + spherical harmonics + radial basis, 1 barrier ----
    for (int k = tid; k < KDIM; k += 256) {
        ptabL[k] = g_ptab[k];
        ytabL[k] = g_ytab[k];
    }
    if (tid < 64) {
        int z = z0 + tid;
        float x = r[z * 3 + 0], y = r[z * 3 + 1], zc = r[z * 3 + 2];
        float rad = sqrtf(x * x + y * y + zc * zc);
        float inv = 1.0f / (rad + 1e-12f);
        float nx = x * inv, ny = y * inv, nz = zc * inv;
        const float c0 = 0.28209479177387814f, c1 = 0.4886025119029199f;
        const float c2a = 1.0925484305920792f, c2b = 0.31539156525252005f, c2c = 0.5462742152960396f;
        Yl[tid][0] = c0;
        Yl[tid][1] = c1 * ny;
        Yl[tid][2] = c1 * nz;
        Yl[tid][3] = c1 * nx;
        Yl[tid][4] = c2a * nx * ny;
        Yl[tid][5] = c2a * ny * nz;
        Yl[tid][6] = c2b * (3.0f * nz * nz - 1.0f);
        Yl[tid][7] = c2a * nx * nz;
        Yl[tid][8] = c2c * (nx * nx - ny * ny);
    }
    {   // Gaussian radial basis -> bf16 Blds (each thread re-derives its radius; no radl)
        int zz = tid >> 2, grp = tid & 3;
        int z = z0 + zz;
        float x = r[z * 3 + 0], y = r[z * 3 + 1], zc = r[z * 3 + 2];
        float rad = sqrtf(x * x + y * y + zc * zc);
        const float step = 3.5f / 63.0f;
        const float NL2E = -5.770780163555852f;   // -4 * log2(e)
        unsigned int* dst = (unsigned int*)&sm.p1.Blds[zz][grp * 16];
        #pragma unroll
        for (int ii = 0; ii < 8; ii++) {
            int i0 = grp * 16 + ii * 2;
            float d0 = rad - (float)i0 * step;
            float d1 = rad - (float)(i0 + 1) * step;
            unsigned int u0 = f2bf(__builtin_amdgcn_exp2f(d0 * d0 * NL2E));
            unsigned int u1 = f2bf(__builtin_amdgcn_exp2f(d1 * d1 * NL2E));
            dst[ii] = u0 | (u1 << 16);
        }
    }
    __syncthreads();

    // ---- Phase B: H = relu(B @ W1 + b1); W1 fragments straight from global ----
    {
        bf16x8 a0 = *(const bf16x8*)&sm.p1.Blds[wv * 16 + l16][0 + quad * 8];
        bf16x8 a1 = *(const bf16x8*)&sm.p1.Blds[wv * 16 + l16][32 + quad * 8];
        #pragma unroll
        for (int nt = 0; nt < 4; nt++) {
            bf16x8 bb0 = *(const bf16x8*)&g_w1s[((0 * 4 + nt) * 64 + lane) * 8];
            bf16x8 bb1 = *(const bf16x8*)&g_w1s[((1 * 4 + nt) * 64 + lane) * 8];
            f32x4 acc = {0.f, 0.f, 0.f, 0.f};
            acc = __builtin_amdgcn_mfma_f32_16x16x32_bf16(a0, bb0, acc, 0, 0, 0);
            acc = __builtin_amdgcn_mfma_f32_16x16x32_bf16(a1, bb1, acc, 0, 0, 0);
            int h = nt * 16 + l16;
            float bias = b1[h];
            #pragma unroll
            for (int rr = 0; rr < 4; rr++) {
                float v = acc[rr] + bias;
                v = v > 0.0f ? v : 0.0f;
                sm.p1.Hlds[wv * 16 + quad * 4 + rr][h] = f2bf(v);
            }
        }
    }
    __syncthreads();

    // ---- Phase C: R = H @ W2 + b2 -> bf16 Rl ----
    {
        bf16x8 a0 = *(const bf16x8*)&sm.p1.Hlds[wv * 16 + l16][0 + quad * 8];
        bf16x8 a1 = *(const bf16x8*)&sm.p1.Hlds[wv * 16 + l16][32 + quad * 8];
        #pragma unroll
        for (int nt = 0; nt < 4; nt++) {
            bf16x8 bb0 = *(const bf16x8*)&g_w2s[((0 * 4 + nt) * 64 + lane) * 8];
            bf16x8 bb1 = *(const bf16x8*)&g_w2s[((1 * 4 + nt) * 64 + lane) * 8];
            f32x4 acc = {0.f, 0.f, 0.f, 0.f};
            acc = __builtin_amdgcn_mfma_f32_16x16x32_bf16(a0, bb0, acc, 0, 0, 0);
            acc = __builtin_amdgcn_mfma_f32_16x16x32_bf16(a1, bb1, acc, 0, 0, 0);
            int p = nt * 16 + l16;
            if (p < NPATH) {
                float bias = b2[p];
                #pragma unroll
                for (int rr = 0; rr < 4; rr++)
                    Rl[wv * 16 + quad * 4 + rr][p] = f2bf(acc[rr] + bias);
            }
        }
    }
    __syncthreads();

    // ---- Phase D: coeff[z][k] = R[z][p(k)] * Y[z][y(k)] -> bf16, k-pad to 224 ----
    for (int idx = tid; idx < 64 * (KPAD / 2); idx += 256) {
        int z = idx / (KPAD / 2);
        int k = (idx % (KPAD / 2)) * 2;
        unsigned int u = 0;
        if (k < KDIM) {   // KDIM even: pairs never straddle
            float cA = bf2f(Rl[z][ptabL[k]])     * Yl[z][ytabL[k]];
            float cB = bf2f(Rl[z][ptabL[k + 1]]) * Yl[z][ytabL[k + 1]];
            u = (unsigned int)f2bf(cA) | ((unsigned int)f2bf(cB) << 16);
        }
        *(unsigned int*)&sm.Clds[z][k] = u;
    }
    __syncthreads();

    // ---- Phase E: out = coeff @ cg; cg fragments are 16B global loads ----
    const int ntb = wv * 5 + (wv > 0 ? 1 : 0);   // w0: nt 0-5, w1: 6-10, w2: 11-15, w3: 16-20
    const int cnt = (wv == 0) ? 6 : 5;

    f32x4 acc[6][4];
    #pragma unroll
    for (int i = 0; i < 6; i++)
        #pragma unroll
        for (int zt = 0; zt < 4; zt++)
            acc[i][zt] = (f32x4){0.f, 0.f, 0.f, 0.f};

    #pragma unroll
    for (int kc = 0; kc < 7; kc++) {
        bf16x8 az[4];
        #pragma unroll
        for (int zt = 0; zt < 4; zt++)
            az[zt] = *(const bf16x8*)&sm.Clds[zt * 16 + l16][kc * 32 + quad * 8];

        bf16x8 bg[6];
        #pragma unroll
        for (int i = 0; i < 6; i++) {
            int nt = ntb + i; if (nt > NTIL - 1) nt = NTIL - 1;   // clamp keeps load in-bounds
            bg[i] = *(const bf16x8*)&g_cgs[((kc * NTIL + nt) * 64 + lane) * 8];
        }
        #pragma unroll
        for (int i = 0; i < 6; i++) {
            if (i < cnt) {
                #pragma unroll
                for (int zt = 0; zt < 4; zt++)
                    acc[i][zt] = __builtin_amdgcn_mfma_f32_16x16x32_bf16(az[zt], bg[i], acc[i][zt], 0, 0, 0);
            }
        }
    }

    // ---- Epilogue: direct stores from accumulators (no LDS stage, no barriers) ----
    #pragma unroll
    for (int i = 0; i < 6; i++) {
        if (i < cnt) {
            int col = (ntb + i) * 16 + l16;
            if (col < NIJ) {                     // last tile covers cols 320..335
                #pragma unroll
                for (int zt = 0; zt < 4; zt++) {
                    #pragma unroll
                    for (int rr = 0; rr < 4; rr++)
                        out[(z0 + zt * 16 + quad * 4 + rr) * NIJ + col] = acc[i][zt][rr];
                }
            }
        }
    }
}

extern "C" void kernel_launch(void* const* d_in, const int* in_sizes, int n_in,
                              void* d_out, int out_size, void* d_ws, size_t ws_size,
                              hipStream_t stream) {
    const float* r   = (const float*)d_in[0];
    const float* W1  = (const float*)d_in[1];
    const float* b1  = (const float*)d_in[2];
    const float* W2  = (const float*)d_in[3];
    const float* b2  = (const float*)d_in[4];
    const float* cg  = (const float*)d_in[5];
    const float* rf  = (const float*)d_in[6];
    const float* ylm = (const float*)d_in[7];
    float* out = (float*)d_out;

    const int Z = in_sizes[0] / 3;

    prep_kernel<<<327, 256, 0, stream>>>(W1, W2, cg, rf, ylm);
    fused_kernel<<<Z / 64, 256, 0, stream>>>(r, b1, b2, out);
}

// Round 3
// 139.412 us; speedup vs baseline: 1.1670x; 1.1670x over previous
//
#include <hip/hip_runtime.h>

#define NPATH 60
#define KDIM  204
#define KPAD  224      // 7 k-chunks of 32, zero padded
#define NIJ   324
#define NTIL  21       // 21 n-tiles of 16 (324 -> 336)
#define HID   64

#define BHS   88       // Blds/Hlds row stride (u16): 176B = 11*16B aligned, 2-way banks (free)
#define CLS   232      // Clds row stride (u16): 464B = 29*16B aligned, 2-way banks (free)

typedef short bf16x8 __attribute__((ext_vector_type(8)));
typedef float f32x4  __attribute__((ext_vector_type(4)));

// One-time prepped operands in bf16 MFMA B-fragment order (module globals:
// graph-safe, rewritten by prep_kernel every call).
__device__ __align__(16) unsigned short g_w1s[4096];    // 2kc x 4nt x 64lane x 8
__device__ __align__(16) unsigned short g_w2s[4096];
__device__ __align__(16) unsigned short g_cgs[75264];   // 7kc x 21nt x 64lane x 8
__device__ unsigned char g_ptab[KDIM];
__device__ unsigned char g_ytab[KDIM];

// Proven RNE f32->bf16 (round-0 verified). Do NOT replace with
// v_cvt_pk_bf16_f32 asm: round-1 showed that path zeroes the pipeline.
__device__ inline unsigned short f2bf(float f) {
    unsigned int u = __builtin_bit_cast(unsigned int, f);
    u += 0x7fffu + ((u >> 16) & 1u);     // RNE
    return (unsigned short)(u >> 16);
}
__device__ inline float bf2f(unsigned short h) {
    unsigned int u = ((unsigned int)h) << 16;
    return __builtin_bit_cast(float, u);
}

__global__ void prep_kernel(const float* __restrict__ W1, const float* __restrict__ W2,
                            const float* __restrict__ cg, const float* __restrict__ rf,
                            const float* __restrict__ ylm)
{
    int idx = blockIdx.x * 256 + threadIdx.x;
    if (idx < 4096) {                                       // W1 -> fragment order
        int e = idx & 7, ln = (idx >> 3) & 63, nt = (idx >> 9) & 3, kc = idx >> 11;
        int k = kc * 32 + (ln >> 4) * 8 + e;
        int n = nt * 16 + (ln & 15);
        g_w1s[idx] = f2bf(W1[k * HID + n]);
    } else if (idx < 8192) {                                // W2 (n>=60 zero)
        int j = idx - 4096;
        int e = j & 7, ln = (j >> 3) & 63, nt = (j >> 9) & 3, kc = j >> 11;
        int k = kc * 32 + (ln >> 4) * 8 + e;
        int n = nt * 16 + (ln & 15);
        g_w2s[j] = f2bf(n < NPATH ? W2[k * NPATH + n] : 0.0f);
    } else if (idx < 8192 + 75264) {                        // cg (k>=204 / n>=324 zero)
        int j = idx - 8192;
        int e = j & 7, ln = (j >> 3) & 63;
        int nt = (j >> 9) % NTIL;
        int kc = j / (512 * NTIL);
        int k = kc * 32 + (ln >> 4) * 8 + e;
        int n = nt * 16 + (ln & 15);
        g_cgs[j] = f2bf((k < KDIM && n < NIJ) ? cg[k * NIJ + n] : 0.0f);
    } else if (idx < 8192 + 75264 + KDIM) {                 // gather tables
        int k = idx - (8192 + 75264);
        int p = 0, yy = 0;
        for (int q = 0; q < NPATH; q++) if (rf[k * NPATH + q] != 0.0f) p = q;
        for (int q = 0; q < 9; q++)     if (ylm[k * 9 + q]   != 0.0f) yy = q;
        g_ptab[k] = (unsigned char)p;
        g_ytab[k] = (unsigned char)yy;
    }
}

// Phase-overlapped LDS: Blds/Hlds dead before Clds is written.
union SmemU {
    struct {
        unsigned short Blds[64][BHS];   // radial basis, bf16   (11,264 B)
        unsigned short Hlds[64][BHS];   // hidden activations   (11,264 B)
    } p1;                               // 22,528 B
    unsigned short Clds[64][CLS];       // coeff bf16, k-pad 224 (29,696 B)
};

// NOTE: plain __launch_bounds__(256). Round 2 proved (256,4) caps VGPRs at 64
// and spills the 96-reg Phase-E accumulator to scratch (+80 MB HBM writes,
// 52->74 us). Phase E NEEDS ~112 VGPRs.
__global__ __launch_bounds__(256) void fused_kernel(
    const float* __restrict__ r, const float* __restrict__ b1,
    const float* __restrict__ b2, float* __restrict__ out)
{
    __shared__ SmemU sm;
    __shared__ unsigned short Rl[64][61];   // R, bf16
    __shared__ float Yl[64][9];
    __shared__ unsigned char ptabL[KDIM];
    __shared__ unsigned char ytabL[KDIM];

    const int tid  = threadIdx.x;
    const int wv   = tid >> 6;
    const int lane = tid & 63;
    const int quad = lane >> 4;
    const int l16  = lane & 15;
    const int z0   = blockIdx.x * 64;

    // ---- Phase A (merged): tables + spherical harmonics + radial basis, 1 barrier ----
    for (int k = tid; k < KDIM; k += 256) {
        ptabL[k] = g_ptab[k];
        ytabL[k] = g_ytab[k];
    }
    if (tid < 64) {
        int z = z0 + tid;
        float x = r[z * 3 + 0], y = r[z * 3 + 1], zc = r[z * 3 + 2];
        float rad = sqrtf(x * x + y * y + zc * zc);
        float inv = 1.0f / (rad + 1e-12f);
        float nx = x * inv, ny = y * inv, nz = zc * inv;
        const float c0 = 0.28209479177387814f, c1 = 0.4886025119029199f;
        const float c2a = 1.0925484305920792f, c2b = 0.31539156525252005f, c2c = 0.5462742152960396f;
        Yl[tid][0] = c0;
        Yl[tid][1] = c1 * ny;
        Yl[tid][2] = c1 * nz;
        Yl[tid][3] = c1 * nx;
        Yl[tid][4] = c2a * nx * ny;
        Yl[tid][5] = c2a * ny * nz;
        Yl[tid][6] = c2b * (3.0f * nz * nz - 1.0f);
        Yl[tid][7] = c2a * nx * nz;
        Yl[tid][8] = c2c * (nx * nx - ny * ny);
    }
    {   // Gaussian radial basis -> bf16 Blds (each thread re-derives its radius; no radl)
        int zz = tid >> 2, grp = tid & 3;
        int z = z0 + zz;
        float x = r[z * 3 + 0], y = r[z * 3 + 1], zc = r[z * 3 + 2];
        float rad = sqrtf(x * x + y * y + zc * zc);
        const float step = 3.5f / 63.0f;
        const float NL2E = -5.770780163555852f;   // -4 * log2(e)
        unsigned int* dst = (unsigned int*)&sm.p1.Blds[zz][grp * 16];
        #pragma unroll
        for (int ii = 0; ii < 8; ii++) {
            int i0 = grp * 16 + ii * 2;
            float d0 = rad - (float)i0 * step;
            float d1 = rad - (float)(i0 + 1) * step;
            unsigned int u0 = f2bf(__builtin_amdgcn_exp2f(d0 * d0 * NL2E));
            unsigned int u1 = f2bf(__builtin_amdgcn_exp2f(d1 * d1 * NL2E));
            dst[ii] = u0 | (u1 << 16);
        }
    }
    __syncthreads();

    // ---- Phase B: H = relu(B @ W1 + b1); W1 fragments straight from global ----
    {
        bf16x8 a0 = *(const bf16x8*)&sm.p1.Blds[wv * 16 + l16][0 + quad * 8];
        bf16x8 a1 = *(const bf16x8*)&sm.p1.Blds[wv * 16 + l16][32 + quad * 8];
        #pragma unroll
        for (int nt = 0; nt < 4; nt++) {
            bf16x8 bb0 = *(const bf16x8*)&g_w1s[((0 * 4 + nt) * 64 + lane) * 8];
            bf16x8 bb1 = *(const bf16x8*)&g_w1s[((1 * 4 + nt) * 64 + lane) * 8];
            f32x4 acc = {0.f, 0.f, 0.f, 0.f};
            acc = __builtin_amdgcn_mfma_f32_16x16x32_bf16(a0, bb0, acc, 0, 0, 0);
            acc = __builtin_amdgcn_mfma_f32_16x16x32_bf16(a1, bb1, acc, 0, 0, 0);
            int h = nt * 16 + l16;
            float bias = b1[h];
            #pragma unroll
            for (int rr = 0; rr < 4; rr++) {
                float v = acc[rr] + bias;
                v = v > 0.0f ? v : 0.0f;
                sm.p1.Hlds[wv * 16 + quad * 4 + rr][h] = f2bf(v);
            }
        }
    }
    __syncthreads();

    // ---- Phase C: R = H @ W2 + b2 -> bf16 Rl ----
    {
        bf16x8 a0 = *(const bf16x8*)&sm.p1.Hlds[wv * 16 + l16][0 + quad * 8];
        bf16x8 a1 = *(const bf16x8*)&sm.p1.Hlds[wv * 16 + l16][32 + quad * 8];
        #pragma unroll
        for (int nt = 0; nt < 4; nt++) {
            bf16x8 bb0 = *(const bf16x8*)&g_w2s[((0 * 4 + nt) * 64 + lane) * 8];
            bf16x8 bb1 = *(const bf16x8*)&g_w2s[((1 * 4 + nt) * 64 + lane) * 8];
            f32x4 acc = {0.f, 0.f, 0.f, 0.f};
            acc = __builtin_amdgcn_mfma_f32_16x16x32_bf16(a0, bb0, acc, 0, 0, 0);
            acc = __builtin_amdgcn_mfma_f32_16x16x32_bf16(a1, bb1, acc, 0, 0, 0);
            int p = nt * 16 + l16;
            if (p < NPATH) {
                float bias = b2[p];
                #pragma unroll
                for (int rr = 0; rr < 4; rr++)
                    Rl[wv * 16 + quad * 4 + rr][p] = f2bf(acc[rr] + bias);
            }
        }
    }
    __syncthreads();

    // ---- Phase D: coeff[z][k] = R[z][p(k)] * Y[z][y(k)] -> bf16, k-pad to 224 ----
    for (int idx = tid; idx < 64 * (KPAD / 2); idx += 256) {
        int z = idx / (KPAD / 2);
        int k = (idx % (KPAD / 2)) * 2;
        unsigned int u = 0;
        if (k < KDIM) {   // KDIM even: pairs never straddle
            float cA = bf2f(Rl[z][ptabL[k]])     * Yl[z][ytabL[k]];
            float cB = bf2f(Rl[z][ptabL[k + 1]]) * Yl[z][ytabL[k + 1]];
            u = (unsigned int)f2bf(cA) | ((unsigned int)f2bf(cB) << 16);
        }
        *(unsigned int*)&sm.Clds[z][k] = u;
    }
    __syncthreads();

    // ---- Phase E: out = coeff @ cg; cg fragments are 16B global loads ----
    const int ntb = wv * 5 + (wv > 0 ? 1 : 0);   // w0: nt 0-5, w1: 6-10, w2: 11-15, w3: 16-20
    const int cnt = (wv == 0) ? 6 : 5;

    f32x4 acc[6][4];
    #pragma unroll
    for (int i = 0; i < 6; i++)
        #pragma unroll
        for (int zt = 0; zt < 4; zt++)
            acc[i][zt] = (f32x4){0.f, 0.f, 0.f, 0.f};

    #pragma unroll
    for (int kc = 0; kc < 7; kc++) {
        bf16x8 az[4];
        #pragma unroll
        for (int zt = 0; zt < 4; zt++)
            az[zt] = *(const bf16x8*)&sm.Clds[zt * 16 + l16][kc * 32 + quad * 8];

        bf16x8 bg[6];
        #pragma unroll
        for (int i = 0; i < 6; i++) {
            int nt = ntb + i; if (nt > NTIL - 1) nt = NTIL - 1;   // clamp keeps load in-bounds
            bg[i] = *(const bf16x8*)&g_cgs[((kc * NTIL + nt) * 64 + lane) * 8];
        }
        #pragma unroll
        for (int i = 0; i < 6; i++) {
            if (i < cnt) {
                #pragma unroll
                for (int zt = 0; zt < 4; zt++)
                    acc[i][zt] = __builtin_amdgcn_mfma_f32_16x16x32_bf16(az[zt], bg[i], acc[i][zt], 0, 0, 0);
            }
        }
    }

    // ---- Epilogue: direct stores from accumulators (no LDS stage, no barriers) ----
    #pragma unroll
    for (int i = 0; i < 6; i++) {
        if (i < cnt) {
            int col = (ntb + i) * 16 + l16;
            if (col < NIJ) {                     // last tile covers cols 320..335
                #pragma unroll
                for (int zt = 0; zt < 4; zt++) {
                    #pragma unroll
                    for (int rr = 0; rr < 4; rr++)
                        out[(z0 + zt * 16 + quad * 4 + rr) * NIJ + col] = acc[i][zt][rr];
                }
            }
        }
    }
}

extern "C" void kernel_launch(void* const* d_in, const int* in_sizes, int n_in,
                              void* d_out, int out_size, void* d_ws, size_t ws_size,
                              hipStream_t stream) {
    const float* r   = (const float*)d_in[0];
    const float* W1  = (const float*)d_in[1];
    const float* b1  = (const float*)d_in[2];
    const float* W2  = (const float*)d_in[3];
    const float* b2  = (const float*)d_in[4];
    const float* cg  = (const float*)d_in[5];
    const float* rf  = (const float*)d_in[6];
    const float* ylm = (const float*)d_in[7];
    float* out = (float*)d_out;

    const int Z = in_sizes[0] / 3;

    prep_kernel<<<327, 256, 0, stream>>>(W1, W2, cg, rf, ylm);
    fused_kernel<<<Z / 64, 256, 0, stream>>>(r, b1, b2, out);
}

// Round 4
// 139.403 us; speedup vs baseline: 1.1670x; 1.0001x over previous
//
#include <hip/hip_runtime.h>

#define NPATH 60
#define KDIM  204
#define KPAD  224      // 7 k-chunks of 32, zero padded
#define NIJ   324
#define NTIL  21       // 21 n-tiles of 16 (324 -> 336)
#define HID   64

#define BHS   88       // Blds/Hlds row stride (u16): 176B = 11*16B aligned, 2-way banks (free)
#define CLS   232      // Clds row stride (u16): 464B = 29*16B aligned; payload 448B, swizzle-safe

typedef short bf16x8 __attribute__((ext_vector_type(8)));
typedef float f32x4  __attribute__((ext_vector_type(4)));

// One-time prepped operands in bf16 MFMA B-fragment order (module globals:
// graph-safe, rewritten by prep_kernel every call).
__device__ __align__(16) unsigned short g_w1s[4096];    // 2kc x 4nt x 64lane x 8
__device__ __align__(16) unsigned short g_w2s[4096];
__device__ __align__(16) unsigned short g_cgs[75264];   // 7kc x 21nt x 64lane x 8
__device__ unsigned int  g_pyk[112];                    // per k-pair: p0|y0<<8|p1<<16|y1<<24

// Proven RNE f32->bf16 (round-0 verified). Do NOT replace with
// v_cvt_pk_bf16_f32 asm: round-1 showed that path zeroes the pipeline.
__device__ inline unsigned short f2bf(float f) {
    unsigned int u = __builtin_bit_cast(unsigned int, f);
    u += 0x7fffu + ((u >> 16) & 1u);     // RNE
    return (unsigned short)(u >> 16);
}
__device__ inline float bf2f(unsigned short h) {
    unsigned int u = ((unsigned int)h) << 16;
    return __builtin_bit_cast(float, u);
}

__global__ void prep_kernel(const float* __restrict__ W1, const float* __restrict__ W2,
                            const float* __restrict__ cg, const float* __restrict__ rf,
                            const float* __restrict__ ylm)
{
    int idx = blockIdx.x * 256 + threadIdx.x;
    if (idx < 4096) {                                       // W1 -> fragment order
        int e = idx & 7, ln = (idx >> 3) & 63, nt = (idx >> 9) & 3, kc = idx >> 11;
        int k = kc * 32 + (ln >> 4) * 8 + e;
        int n = nt * 16 + (ln & 15);
        g_w1s[idx] = f2bf(W1[k * HID + n]);
    } else if (idx < 8192) {                                // W2 (n>=60 zero)
        int j = idx - 4096;
        int e = j & 7, ln = (j >> 3) & 63, nt = (j >> 9) & 3, kc = j >> 11;
        int k = kc * 32 + (ln >> 4) * 8 + e;
        int n = nt * 16 + (ln & 15);
        g_w2s[j] = f2bf(n < NPATH ? W2[k * NPATH + n] : 0.0f);
    } else if (idx < 8192 + 75264) {                        // cg (k>=204 / n>=324 zero)
        int j = idx - 8192;
        int e = j & 7, ln = (j >> 3) & 63;
        int nt = (j >> 9) % NTIL;
        int kc = j / (512 * NTIL);
        int k = kc * 32 + (ln >> 4) * 8 + e;
        int n = nt * 16 + (ln & 15);
        g_cgs[j] = f2bf((k < KDIM && n < NIJ) ? cg[k * NIJ + n] : 0.0f);
    } else if (idx < 8192 + 75264 + 112) {                  // packed (p,y) per k-pair
        int j = idx - (8192 + 75264);
        int k0 = 2 * j, k1 = 2 * j + 1;
        unsigned p0 = 0, y0 = 0, p1 = 0, y1 = 0;
        if (k0 < KDIM) {
            for (int q = 0; q < NPATH; q++) if (rf[k0 * NPATH + q] != 0.0f) p0 = q;
            for (int q = 0; q < 9; q++)     if (ylm[k0 * 9 + q]   != 0.0f) y0 = q;
            for (int q = 0; q < NPATH; q++) if (rf[k1 * NPATH + q] != 0.0f) p1 = q;
            for (int q = 0; q < 9; q++)     if (ylm[k1 * 9 + q]   != 0.0f) y1 = q;
        }
        g_pyk[j] = p0 | (y0 << 8) | (p1 << 16) | (y1 << 24);
    }
}

// Phase-overlapped LDS: Blds/Hlds dead before Clds is written.
union SmemU {
    struct {
        unsigned short Blds[64][BHS];   // radial basis, bf16   (11,264 B)
        unsigned short Hlds[64][BHS];   // hidden activations   (11,264 B)
    } p1;                               // 22,528 B
    unsigned short Clds[64][CLS];       // coeff bf16, k-pad 224 (29,696 B)
};

// NOTE: plain __launch_bounds__(256). Round 2 proved (256,4) caps VGPRs at 64
// and spills the Phase-E accumulators to scratch (+80 MB HBM writes, 52->74 us).
__global__ __launch_bounds__(256) void fused_kernel(
    const float* __restrict__ r, const float* __restrict__ b1,
    const float* __restrict__ b2, float* __restrict__ out)
{
    __shared__ SmemU sm;
    __shared__ unsigned short Rl[64][61];   // R, bf16 (row stride 122B: odd dwords -> 2-way)
    __shared__ float Yl[64][9];             // row stride 36B: odd dwords -> 2-way
    __shared__ unsigned int pyL[112];

    const int tid  = threadIdx.x;
    const int wv   = tid >> 6;
    const int lane = tid & 63;
    const int quad = lane >> 4;
    const int l16  = lane & 15;
    const int z0   = blockIdx.x * 64;

    // ---- Phase A (merged): py table + spherical harmonics + radial basis, 1 barrier ----
    if (tid < 112) pyL[tid] = g_pyk[tid];
    if (tid < 64) {
        int z = z0 + tid;
        float x = r[z * 3 + 0], y = r[z * 3 + 1], zc = r[z * 3 + 2];
        float rad = sqrtf(x * x + y * y + zc * zc);
        float inv = 1.0f / (rad + 1e-12f);
        float nx = x * inv, ny = y * inv, nz = zc * inv;
        const float c0 = 0.28209479177387814f, c1 = 0.4886025119029199f;
        const float c2a = 1.0925484305920792f, c2b = 0.31539156525252005f, c2c = 0.5462742152960396f;
        Yl[tid][0] = c0;
        Yl[tid][1] = c1 * ny;
        Yl[tid][2] = c1 * nz;
        Yl[tid][3] = c1 * nx;
        Yl[tid][4] = c2a * nx * ny;
        Yl[tid][5] = c2a * ny * nz;
        Yl[tid][6] = c2b * (3.0f * nz * nz - 1.0f);
        Yl[tid][7] = c2a * nx * nz;
        Yl[tid][8] = c2c * (nx * nx - ny * ny);
    }
    {   // Gaussian radial basis -> bf16 Blds (each thread re-derives its radius)
        int zz = tid >> 2, grp = tid & 3;
        int z = z0 + zz;
        float x = r[z * 3 + 0], y = r[z * 3 + 1], zc = r[z * 3 + 2];
        float rad = sqrtf(x * x + y * y + zc * zc);
        const float step = 3.5f / 63.0f;
        const float NL2E = -5.770780163555852f;   // -4 * log2(e)
        unsigned int* dst = (unsigned int*)&sm.p1.Blds[zz][grp * 16];
        #pragma unroll
        for (int ii = 0; ii < 8; ii++) {
            int i0 = grp * 16 + ii * 2;
            float d0 = rad - (float)i0 * step;
            float d1 = rad - (float)(i0 + 1) * step;
            unsigned int u0 = f2bf(__builtin_amdgcn_exp2f(d0 * d0 * NL2E));
            unsigned int u1 = f2bf(__builtin_amdgcn_exp2f(d1 * d1 * NL2E));
            dst[ii] = u0 | (u1 << 16);
        }
    }
    __syncthreads();

    // ---- Phase B: H = relu(B @ W1 + b1); W1 fragments straight from global ----
    {
        bf16x8 a0 = *(const bf16x8*)&sm.p1.Blds[wv * 16 + l16][0 + quad * 8];
        bf16x8 a1 = *(const bf16x8*)&sm.p1.Blds[wv * 16 + l16][32 + quad * 8];
        #pragma unroll
        for (int nt = 0; nt < 4; nt++) {
            bf16x8 bb0 = *(const bf16x8*)&g_w1s[((0 * 4 + nt) * 64 + lane) * 8];
            bf16x8 bb1 = *(const bf16x8*)&g_w1s[((1 * 4 + nt) * 64 + lane) * 8];
            f32x4 acc = {0.f, 0.f, 0.f, 0.f};
            acc = __builtin_amdgcn_mfma_f32_16x16x32_bf16(a0, bb0, acc, 0, 0, 0);
            acc = __builtin_amdgcn_mfma_f32_16x16x32_bf16(a1, bb1, acc, 0, 0, 0);
            int h = nt * 16 + l16;
            float bias = b1[h];
            #pragma unroll
            for (int rr = 0; rr < 4; rr++) {
                float v = acc[rr] + bias;
                v = v > 0.0f ? v : 0.0f;
                sm.p1.Hlds[wv * 16 + quad * 4 + rr][h] = f2bf(v);
            }
        }
    }
    __syncthreads();

    // ---- Phase C: R = H @ W2 + b2 -> bf16 Rl ----
    {
        bf16x8 a0 = *(const bf16x8*)&sm.p1.Hlds[wv * 16 + l16][0 + quad * 8];
        bf16x8 a1 = *(const bf16x8*)&sm.p1.Hlds[wv * 16 + l16][32 + quad * 8];
        #pragma unroll
        for (int nt = 0; nt < 4; nt++) {
            bf16x8 bb0 = *(const bf16x8*)&g_w2s[((0 * 4 + nt) * 64 + lane) * 8];
            bf16x8 bb1 = *(const bf16x8*)&g_w2s[((1 * 4 + nt) * 64 + lane) * 8];
            f32x4 acc = {0.f, 0.f, 0.f, 0.f};
            acc = __builtin_amdgcn_mfma_f32_16x16x32_bf16(a0, bb0, acc, 0, 0, 0);
            acc = __builtin_amdgcn_mfma_f32_16x16x32_bf16(a1, bb1, acc, 0, 0, 0);
            int p = nt * 16 + l16;
            if (p < NPATH) {
                float bias = b2[p];
                #pragma unroll
                for (int rr = 0; rr < 4; rr++)
                    Rl[wv * 16 + quad * 4 + rr][p] = f2bf(acc[rr] + bias);
            }
        }
    }
    __syncthreads();

    // ---- Phase D: coeff[z][k] = R[z][p(k)] * Y[z][y(k)] -> bf16, z = lane ----
    // Wave wv owns k-pairs j = wv*28 .. +27. Table read is wave-uniform (broadcast).
    // Column write conflict fixed by XOR of byte-bits 4-5 keyed on (z>>3)&3
    // (bijective within the 448-B row payload; Phase E reads apply the same XOR).
    {
        const int j0 = wv * 28;
        char* rowp = (char*)&sm.Clds[lane][0];
        const unsigned key = ((lane >> 3) & 3) << 4;
        #pragma unroll
        for (int jj = 0; jj < 28; ++jj) {
            int j = j0 + jj;
            int k = 2 * j;
            unsigned u = 0;
            if (k < KDIM) {
                unsigned py = pyL[j];
                float cA = bf2f(Rl[lane][py & 255])         * Yl[lane][(py >> 8) & 255];
                float cB = bf2f(Rl[lane][(py >> 16) & 255]) * Yl[lane][(py >> 24)];
                u = (unsigned int)f2bf(cA) | ((unsigned int)f2bf(cB) << 16);
            }
            *(unsigned int*)(rowp + (((unsigned)(2 * k)) ^ key)) = u;
        }
    }
    __syncthreads();

    // ---- Phase E: out = coeff @ cg, split into two halves; stores of half 0
    //      overlap the compute of half 1 (fire-and-forget global writes) ----
    const int ntb = wv * 5 + (wv > 0 ? 1 : 0);   // w0: nt 0-5, w1: 6-10, w2: 11-15, w3: 16-20
    const int cnt = (wv == 0) ? 6 : 5;

    #pragma unroll
    for (int half = 0; half < 2; half++) {
        f32x4 acc[3][4];
        #pragma unroll
        for (int ii = 0; ii < 3; ii++)
            #pragma unroll
            for (int zt = 0; zt < 4; zt++)
                acc[ii][zt] = (f32x4){0.f, 0.f, 0.f, 0.f};

        #pragma unroll
        for (int kc = 0; kc < 7; kc++) {
            bf16x8 az[4];
            #pragma unroll
            for (int zt = 0; zt < 4; zt++) {
                int z = zt * 16 + l16;
                unsigned boff = ((unsigned)(kc * 64 + quad * 16)) ^ (((unsigned)((z >> 3) & 3)) << 4);
                az[zt] = *(const bf16x8*)((const char*)&sm.Clds[z][0] + boff);
            }
            bf16x8 bg[3];
            #pragma unroll
            for (int ii = 0; ii < 3; ii++) {
                int nt = ntb + half * 3 + ii; if (nt > NTIL - 1) nt = NTIL - 1;  // in-bounds clamp
                bg[ii] = *(const bf16x8*)&g_cgs[((kc * NTIL + nt) * 64 + lane) * 8];
            }
            #pragma unroll
            for (int ii = 0; ii < 3; ii++) {
                if (half * 3 + ii < cnt) {
                    #pragma unroll
                    for (int zt = 0; zt < 4; zt++)
                        acc[ii][zt] = __builtin_amdgcn_mfma_f32_16x16x32_bf16(az[zt], bg[ii], acc[ii][zt], 0, 0, 0);
                }
            }
        }

        #pragma unroll
        for (int ii = 0; ii < 3; ii++) {
            if (half * 3 + ii < cnt) {
                int col = (ntb + half * 3 + ii) * 16 + l16;
                if (col < NIJ) {                 // last tile covers cols 320..335
                    #pragma unroll
                    for (int zt = 0; zt < 4; zt++) {
                        #pragma unroll
                        for (int rr = 0; rr < 4; rr++)
                            out[(z0 + zt * 16 + quad * 4 + rr) * NIJ + col] = acc[ii][zt][rr];
                    }
                }
            }
        }
    }
}

extern "C" void kernel_launch(void* const* d_in, const int* in_sizes, int n_in,
                              void* d_out, int out_size, void* d_ws, size_t ws_size,
                              hipStream_t stream) {
    const float* r   = (const float*)d_in[0];
    const float* W1  = (const float*)d_in[1];
    const float* b1  = (const float*)d_in[2];
    const float* W2  = (const float*)d_in[3];
    const float* b2  = (const float*)d_in[4];
    const float* cg  = (const float*)d_in[5];
    const float* rf  = (const float*)d_in[6];
    const float* ylm = (const float*)d_in[7];
    float* out = (float*)d_out;

    const int Z = in_sizes[0] / 3;

    prep_kernel<<<327, 256, 0, stream>>>(W1, W2, cg, rf, ylm);
    fused_kernel<<<Z / 64, 256, 0, stream>>>(r, b1, b2, out);
}

// Round 5
// 138.160 us; speedup vs baseline: 1.1775x; 1.0090x over previous
//
#include <hip/hip_runtime.h>

#define NPATH 60
#define KDIM  204
#define NIJ   324
#define NTIL  21       // 21 n-tiles of 16 (324 -> 336)
#define HID   64

typedef short bf16x8 __attribute__((ext_vector_type(8)));
typedef float f32x4  __attribute__((ext_vector_type(4)));

// One-time prepped operands in bf16 MFMA B-fragment order (module globals:
// graph-safe, rewritten by prep_kernel every call).
__device__ __align__(16) unsigned short g_w1s[4096];    // 2kc x 4nt x 64lane x 8
__device__ __align__(16) unsigned short g_w2s[4096];
__device__ __align__(16) unsigned short g_cgs[75264];   // 7kc x 21nt x 64lane x 8
__device__ unsigned int  g_pyk[112];                    // per k-pair: p0|y0<<8|p1<<16|y1<<24

// Proven RNE f32->bf16 (round-0 verified). Do NOT replace with
// v_cvt_pk_bf16_f32 asm: round-1 showed that path zeroes the pipeline.
__device__ inline unsigned short f2bf(float f) {
    unsigned int u = __builtin_bit_cast(unsigned int, f);
    u += 0x7fffu + ((u >> 16) & 1u);     // RNE
    return (unsigned short)(u >> 16);
}
__device__ inline float bf2f(unsigned short h) {
    unsigned int u = ((unsigned int)h) << 16;
    return __builtin_bit_cast(float, u);
}

__global__ void prep_kernel(const float* __restrict__ W1, const float* __restrict__ W2,
                            const float* __restrict__ cg, const float* __restrict__ rf,
                            const float* __restrict__ ylm)
{
    int idx = blockIdx.x * 256 + threadIdx.x;
    if (idx < 4096) {                                       // W1 -> fragment order
        int e = idx & 7, ln = (idx >> 3) & 63, nt = (idx >> 9) & 3, kc = idx >> 11;
        int k = kc * 32 + (ln >> 4) * 8 + e;
        int n = nt * 16 + (ln & 15);
        g_w1s[idx] = f2bf(W1[k * HID + n]);
    } else if (idx < 8192) {                                // W2 (n>=60 zero)
        int j = idx - 4096;
        int e = j & 7, ln = (j >> 3) & 63, nt = (j >> 9) & 3, kc = j >> 11;
        int k = kc * 32 + (ln >> 4) * 8 + e;
        int n = nt * 16 + (ln & 15);
        g_w2s[j] = f2bf(n < NPATH ? W2[k * NPATH + n] : 0.0f);
    } else if (idx < 8192 + 75264) {                        // cg (k>=204 / n>=324 zero)
        int j = idx - 8192;
        int e = j & 7, ln = (j >> 3) & 63;
        int nt = (j >> 9) % NTIL;
        int kc = j / (512 * NTIL);
        int k = kc * 32 + (ln >> 4) * 8 + e;
        int n = nt * 16 + (ln & 15);
        g_cgs[j] = f2bf((k < KDIM && n < NIJ) ? cg[k * NIJ + n] : 0.0f);
    } else if (idx < 8192 + 75264 + 112) {                  // packed (p,y) per k-pair
        int j = idx - (8192 + 75264);
        int k0 = 2 * j, k1 = 2 * j + 1;
        unsigned p0 = 0, y0 = 0, p1 = 0, y1 = 0;
        if (k0 < KDIM) {
            for (int q = 0; q < NPATH; q++) if (rf[k0 * NPATH + q] != 0.0f) p0 = q;
            for (int q = 0; q < 9; q++)     if (ylm[k0 * 9 + q]   != 0.0f) y0 = q;
            for (int q = 0; q < NPATH; q++) if (rf[k1 * NPATH + q] != 0.0f) p1 = q;
            for (int q = 0; q < 9; q++)     if (ylm[k1 * 9 + q]   != 0.0f) y1 = q;
        }
        g_pyk[j] = p0 | (y0 << 8) | (p1 << 16) | (y1 << 24);
    }
}

// Per-wave LDS slice. Hw (phase B->C) is dead before Cw (phase D->E) is
// written BY THE SAME WAVE, so they union per-wave (no cross-wave aliasing,
// no barrier needed for the overlay).
// Cw row stride 224 u16 = 448 B = 28x16B (b128-aligned). 448B = 112 dwords,
// 112 mod 32 = 16 -> row bank base = 16*(l16&1). Phase-E b128 reads at
// (kc*64+quad*16)^((l16>>2)&3)<<4: start bank = 16*(l16&1)+4*(quad^g) ->
// exactly 8 accesses per 4-bank group = uniform minimum (conflict-free).
// Phase-D dword writes XOR the same key on dword-index bits 2-3, which
// separates the (l16, l16+8) and (l16, l16+4) row pairs -> ~2-way (free).
struct __align__(16) WaveMem {
    union {
        unsigned short Hw[16][88];   // 2816 B  (88 u16 = 176 B = 11x16B aligned)
        unsigned short Cw[16][224];  // 7168 B
    } u;
    unsigned short Rw[16][61];       // 1952 B (stride 122 B: 16 rows -> 16 distinct banks)
    float          Yw[16][9];        // 576 B  (stride 36 B: 9*l16 mod 32 distinct)
};                                   // 9696 B per wave; x4 = 38784 B

// Plain __launch_bounds__(256): round 2 proved (256,4) caps VGPR at 64 and
// spills Phase-E accumulators (+80 MB scratch traffic).
__global__ __launch_bounds__(256) void fused_kernel(
    const float* __restrict__ r, const float* __restrict__ b1,
    const float* __restrict__ b2, float* __restrict__ out)
{
    __shared__ WaveMem wm[4];
    __shared__ unsigned int pyw[112];    // all waves write identical data (benign)

    const int tid  = threadIdx.x;
    const int wv   = tid >> 6;
    const int lane = tid & 63;
    const int quad = lane >> 4;
    const int l16  = lane & 15;
    const int z0   = blockIdx.x * 64;

    // ---- Phase A (wave-local): py table, Y -> Yw, B-basis fragments in REGISTERS ----
    pyw[lane] = g_pyk[lane];
    if (lane < 48) pyw[64 + lane] = g_pyk[64 + lane];

    const int zloc = wv * 16 + l16;          // this lane's z row (4x redundant over quads)
    const int zg   = z0 + zloc;
    float x = r[zg * 3 + 0], y = r[zg * 3 + 1], zc = r[zg * 3 + 2];
    float rad = sqrtf(x * x + y * y + zc * zc);

    if (quad == 0) {                          // 16 lanes write Y for their row
        float inv = 1.0f / (rad + 1e-12f);
        float nx = x * inv, ny = y * inv, nz = zc * inv;
        const float c0 = 0.28209479177387814f, c1 = 0.4886025119029199f;
        const float c2a = 1.0925484305920792f, c2b = 0.31539156525252005f, c2c = 0.5462742152960396f;
        wm[wv].Yw[l16][0] = c0;
        wm[wv].Yw[l16][1] = c1 * ny;
        wm[wv].Yw[l16][2] = c1 * nz;
        wm[wv].Yw[l16][3] = c1 * nx;
        wm[wv].Yw[l16][4] = c2a * nx * ny;
        wm[wv].Yw[l16][5] = c2a * ny * nz;
        wm[wv].Yw[l16][6] = c2b * (3.0f * nz * nz - 1.0f);
        wm[wv].Yw[l16][7] = c2a * nx * nz;
        wm[wv].Yw[l16][8] = c2c * (nx * nx - ny * ny);
    }

    // MFMA A-fragment for Phase B, built directly in registers: element e of
    // A0 is B[z=l16][i=quad*8+e], A1 covers i=32+quad*8+e. No LDS roundtrip.
    union { bf16x8 v; unsigned int d[4]; } A0, A1;
    {
        const float step = 3.5f / 63.0f;
        const float NL2E = -5.770780163555852f;   // -4 * log2(e)
        #pragma unroll
        for (int ii = 0; ii < 4; ii++) {
            int i0 = quad * 8 + 2 * ii;
            float d0 = rad - (float)i0 * step;
            float d1 = rad - (float)(i0 + 1) * step;
            A0.d[ii] = (unsigned)f2bf(__builtin_amdgcn_exp2f(d0 * d0 * NL2E))
                     | ((unsigned)f2bf(__builtin_amdgcn_exp2f(d1 * d1 * NL2E)) << 16);
            int i2 = 32 + i0;
            float e0 = rad - (float)i2 * step;
            float e1 = rad - (float)(i2 + 1) * step;
            A1.d[ii] = (unsigned)f2bf(__builtin_amdgcn_exp2f(e0 * e0 * NL2E))
                     | ((unsigned)f2bf(__builtin_amdgcn_exp2f(e1 * e1 * NL2E)) << 16);
        }
    }

    // ---- Phase B (wave-local): H = relu(B @ W1 + b1) -> Hw ----
    #pragma unroll
    for (int nt = 0; nt < 4; nt++) {
        bf16x8 bb0 = *(const bf16x8*)&g_w1s[((0 * 4 + nt) * 64 + lane) * 8];
        bf16x8 bb1 = *(const bf16x8*)&g_w1s[((1 * 4 + nt) * 64 + lane) * 8];
        f32x4 acc = {0.f, 0.f, 0.f, 0.f};
        acc = __builtin_amdgcn_mfma_f32_16x16x32_bf16(A0.v, bb0, acc, 0, 0, 0);
        acc = __builtin_amdgcn_mfma_f32_16x16x32_bf16(A1.v, bb1, acc, 0, 0, 0);
        int h = nt * 16 + l16;
        float bias = b1[h];
        #pragma unroll
        for (int rr = 0; rr < 4; rr++) {
            float v = acc[rr] + bias;
            v = v > 0.0f ? v : 0.0f;
            wm[wv].u.Hw[quad * 4 + rr][h] = f2bf(v);
        }
    }
    // Cross-LANE (same wave) visibility: wave issues LDS ops in order; drain them.
    asm volatile("s_waitcnt lgkmcnt(0)" ::: "memory");
    __builtin_amdgcn_sched_barrier(0);

    // ---- Phase C (wave-local): R = H @ W2 + b2 -> Rw ----
    {
        bf16x8 h0 = *(const bf16x8*)&wm[wv].u.Hw[l16][0 + quad * 8];
        bf16x8 h1 = *(const bf16x8*)&wm[wv].u.Hw[l16][32 + quad * 8];
        #pragma unroll
        for (int nt = 0; nt < 4; nt++) {
            bf16x8 bb0 = *(const bf16x8*)&g_w2s[((0 * 4 + nt) * 64 + lane) * 8];
            bf16x8 bb1 = *(const bf16x8*)&g_w2s[((1 * 4 + nt) * 64 + lane) * 8];
            f32x4 acc = {0.f, 0.f, 0.f, 0.f};
            acc = __builtin_amdgcn_mfma_f32_16x16x32_bf16(h0, bb0, acc, 0, 0, 0);
            acc = __builtin_amdgcn_mfma_f32_16x16x32_bf16(h1, bb1, acc, 0, 0, 0);
            int p = nt * 16 + l16;
            if (p < NPATH) {
                float bias = b2[p];
                #pragma unroll
                for (int rr = 0; rr < 4; rr++)
                    wm[wv].Rw[quad * 4 + rr][p] = f2bf(acc[rr] + bias);
            }
        }
    }
    asm volatile("s_waitcnt lgkmcnt(0)" ::: "memory");
    __builtin_amdgcn_sched_barrier(0);

    // ---- Phase D (wave-local): coeff[z][k] = R[z][p(k)] * Y[z][y(k)] -> own Cw rows ----
    // Lane (quad,l16) writes row l16 of its wave's tile, dwords j = quad*28+jj,
    // at physical dword j ^ gkey (16B-group swizzle, consistent with Phase E).
    {
        const unsigned gkey = ((unsigned)((l16 >> 2) & 3)) << 2;   // dword-index XOR (bits 2-3)
        unsigned int* crow = (unsigned int*)&wm[wv].u.Cw[l16][0];
        #pragma unroll
        for (int jj = 0; jj < 28; jj++) {
            int j = quad * 28 + jj;
            unsigned u = 0;
            if (2 * j < KDIM) {
                unsigned py = pyw[j];
                float cA = bf2f(wm[wv].Rw[l16][py & 255])          * wm[wv].Yw[l16][(py >> 8) & 255];
                float cB = bf2f(wm[wv].Rw[l16][(py >> 16) & 255])  * wm[wv].Yw[l16][py >> 24];
                u = (unsigned)f2bf(cA) | ((unsigned)f2bf(cB) << 16);
            }
            crow[j ^ gkey] = u;
        }
    }

    // The ONLY block-wide barrier: Phase E reads all 4 waves' Cw tiles.
    __syncthreads();

    // ---- Phase E: out = coeff @ cg (wave = nt-band, all 4 z-tiles) ----
    const int ntb = wv * 5 + (wv > 0 ? 1 : 0);   // w0: nt 0-5, w1: 6-10, w2: 11-15, w3: 16-20
    const int cnt = (wv == 0) ? 6 : 5;
    const unsigned bkey = ((unsigned)((l16 >> 2) & 3)) << 4;   // byte XOR for 16B groups

    #pragma unroll
    for (int half = 0; half < 2; half++) {
        f32x4 acc[3][4];
        #pragma unroll
        for (int ii = 0; ii < 3; ii++)
            #pragma unroll
            for (int zt = 0; zt < 4; zt++)
                acc[ii][zt] = (f32x4){0.f, 0.f, 0.f, 0.f};

        #pragma unroll
        for (int kc = 0; kc < 7; kc++) {
            bf16x8 az[4];
            #pragma unroll
            for (int zt = 0; zt < 4; zt++) {
                unsigned boff = ((unsigned)(kc * 64 + quad * 16)) ^ bkey;
                az[zt] = *(const bf16x8*)((const char*)&wm[zt].u.Cw[l16][0] + boff);
            }
            bf16x8 bg[3];
            #pragma unroll
            for (int ii = 0; ii < 3; ii++) {
                int nt = ntb + half * 3 + ii; if (nt > NTIL - 1) nt = NTIL - 1;  // in-bounds clamp
                bg[ii] = *(const bf16x8*)&g_cgs[((kc * NTIL + nt) * 64 + lane) * 8];
            }
            #pragma unroll
            for (int ii = 0; ii < 3; ii++) {
                if (half * 3 + ii < cnt) {
                    #pragma unroll
                    for (int zt = 0; zt < 4; zt++)
                        acc[ii][zt] = __builtin_amdgcn_mfma_f32_16x16x32_bf16(az[zt], bg[ii], acc[ii][zt], 0, 0, 0);
                }
            }
        }

        #pragma unroll
        for (int ii = 0; ii < 3; ii++) {
            if (half * 3 + ii < cnt) {
                int col = (ntb + half * 3 + ii) * 16 + l16;
                if (col < NIJ) {                 // last tile covers cols 320..335
                    #pragma unroll
                    for (int zt = 0; zt < 4; zt++) {
                        #pragma unroll
                        for (int rr = 0; rr < 4; rr++)
                            out[(z0 + zt * 16 + quad * 4 + rr) * NIJ + col] = acc[ii][zt][rr];
                    }
                }
            }
        }
    }
}

extern "C" void kernel_launch(void* const* d_in, const int* in_sizes, int n_in,
                              void* d_out, int out_size, void* d_ws, size_t ws_size,
                              hipStream_t stream) {
    const float* r   = (const float*)d_in[0];
    const float* W1  = (const float*)d_in[1];
    const float* b1  = (const float*)d_in[2];
    const float* W2  = (const float*)d_in[3];
    const float* b2  = (const float*)d_in[4];
    const float* cg  = (const float*)d_in[5];
    const float* rf  = (const float*)d_in[6];
    const float* ylm = (const float*)d_in[7];
    float* out = (float*)d_out;

    const int Z = in_sizes[0] / 3;

    prep_kernel<<<327, 256, 0, stream>>>(W1, W2, cg, rf, ylm);
    fused_kernel<<<Z / 64, 256, 0, stream>>>(r, b1, b2, out);
}

// Round 6
// 127.213 us; speedup vs baseline: 1.2789x; 1.0861x over previous
//
#include <hip/hip_runtime.h>

#define NPATH 60
#define KDIM  204
#define NIJ   324
#define NTIL  21       // 21 n-tiles of 16 (324 -> 336)
#define HID   64

typedef short bf16x8 __attribute__((ext_vector_type(8)));
typedef float f32x4  __attribute__((ext_vector_type(4)));

// One-time prepped operands in bf16 MFMA B-fragment order (module globals:
// graph-safe, rewritten by prep_kernel every call).
__device__ __align__(16) unsigned short g_w1s[4096];    // 2kc x 4nt x 64lane x 8
__device__ __align__(16) unsigned short g_w2s[4096];
__device__ __align__(16) unsigned short g_cgs[75264];   // 7kc x 21nt x 64lane x 8
__device__ unsigned int  g_pyk[112];                    // per k-pair: p0|y0<<8|p1<<16|y1<<24

// Proven RNE f32->bf16 (round-0 verified). Do NOT replace with
// v_cvt_pk_bf16_f32 asm: round-1 showed that path zeroes the pipeline.
__device__ inline unsigned short f2bf(float f) {
    unsigned int u = __builtin_bit_cast(unsigned int, f);
    u += 0x7fffu + ((u >> 16) & 1u);     // RNE
    return (unsigned short)(u >> 16);
}
__device__ inline float bf2f(unsigned short h) {
    unsigned int u = ((unsigned int)h) << 16;
    return __builtin_bit_cast(float, u);
}

__global__ void prep_kernel(const float* __restrict__ W1, const float* __restrict__ W2,
                            const float* __restrict__ cg, const float* __restrict__ rf,
                            const float* __restrict__ ylm)
{
    int idx = blockIdx.x * 256 + threadIdx.x;
    if (idx < 4096) {                                       // W1 -> fragment order
        int e = idx & 7, ln = (idx >> 3) & 63, nt = (idx >> 9) & 3, kc = idx >> 11;
        int k = kc * 32 + (ln >> 4) * 8 + e;
        int n = nt * 16 + (ln & 15);
        g_w1s[idx] = f2bf(W1[k * HID + n]);
    } else if (idx < 8192) {                                // W2 (n>=60 zero)
        int j = idx - 4096;
        int e = j & 7, ln = (j >> 3) & 63, nt = (j >> 9) & 3, kc = j >> 11;
        int k = kc * 32 + (ln >> 4) * 8 + e;
        int n = nt * 16 + (ln & 15);
        g_w2s[j] = f2bf(n < NPATH ? W2[k * NPATH + n] : 0.0f);
    } else if (idx < 8192 + 75264) {                        // cg (k>=204 / n>=324 zero)
        int j = idx - 8192;
        int e = j & 7, ln = (j >> 3) & 63;
        int nt = (j >> 9) % NTIL;
        int kc = j / (512 * NTIL);
        int k = kc * 32 + (ln >> 4) * 8 + e;
        int n = nt * 16 + (ln & 15);
        g_cgs[j] = f2bf((k < KDIM && n < NIJ) ? cg[k * NIJ + n] : 0.0f);
    } else if (idx < 8192 + 75264 + 112) {                  // packed (p,y) per k-pair
        int j = idx - (8192 + 75264);
        int k0 = 2 * j, k1 = 2 * j + 1;
        unsigned p0 = 0, y0 = 0, p1 = 0, y1 = 0;
        if (k0 < KDIM) {
            for (int q = 0; q < NPATH; q++) if (rf[k0 * NPATH + q] != 0.0f) p0 = q;
            for (int q = 0; q < 9; q++)     if (ylm[k0 * 9 + q]   != 0.0f) y0 = q;
            for (int q = 0; q < NPATH; q++) if (rf[k1 * NPATH + q] != 0.0f) p1 = q;
            for (int q = 0; q < 9; q++)     if (ylm[k1 * 9 + q]   != 0.0f) y1 = q;
        }
        g_pyk[j] = p0 | (y0 << 8) | (p1 << 16) | (y1 << 24);
    }
}

// Per-wave LDS slice only -- NO cross-wave shared state, NO coeff LDS:
// the coeff matrix lives in registers as MFMA A-fragments.
// Hw stride 88 u16 = 176 B: row-starts l16*44 dwords mod 32 -> (l16, l16+8)
// pairs share a bank start = exact 2-way (free, m136).
struct __align__(16) WaveMem {
    unsigned short Hw[16][88];   // 2816 B  hidden activations (B -> C)
    unsigned short Rw[16][61];   // 1952 B  radial path weights (C -> D)
    float          Yw[16][9];    //  576 B  spherical harmonics (A -> D)
};                               // 5344 B per wave; x4 = 21376 B

// Plain __launch_bounds__(256): round 2 proved forcing low VGPR spills the
// accumulators (+80 MB scratch traffic).
__global__ __launch_bounds__(256) void fused_kernel(
    const float* __restrict__ r, const float* __restrict__ b1,
    const float* __restrict__ b2, float* __restrict__ out)
{
    __shared__ WaveMem wm[4];

    const int tid  = threadIdx.x;
    const int wv   = tid >> 6;
    const int lane = tid & 63;
    const int quad = lane >> 4;
    const int l16  = lane & 15;
    const int z0   = blockIdx.x * 64;
    WaveMem& W = wm[wv];

    // ---- Phase A (wave-local; ZERO barriers in this kernel) ----
    const int zg = z0 + wv * 16 + l16;     // lane serves z-row l16 of the wave tile
    float x = r[zg * 3 + 0], y = r[zg * 3 + 1], zc = r[zg * 3 + 2];
    float rad = sqrtf(x * x + y * y + zc * zc);

    if (quad == 0) {                       // 16 lanes write Y for their row
        float inv = 1.0f / (rad + 1e-12f);
        float nx = x * inv, ny = y * inv, nz = zc * inv;
        const float c0 = 0.28209479177387814f, c1 = 0.4886025119029199f;
        const float c2a = 1.0925484305920792f, c2b = 0.31539156525252005f, c2c = 0.5462742152960396f;
        W.Yw[l16][0] = c0;
        W.Yw[l16][1] = c1 * ny;
        W.Yw[l16][2] = c1 * nz;
        W.Yw[l16][3] = c1 * nx;
        W.Yw[l16][4] = c2a * nx * ny;
        W.Yw[l16][5] = c2a * ny * nz;
        W.Yw[l16][6] = c2b * (3.0f * nz * nz - 1.0f);
        W.Yw[l16][7] = c2a * nx * nz;
        W.Yw[l16][8] = c2c * (nx * nx - ny * ny);
    }

    // B-basis MFMA A-fragments in registers (A row = l16, col = quad*8+e).
    union frag { bf16x8 v; unsigned int d[4]; };
    frag A0, A1;
    {
        const float step = 3.5f / 63.0f;
        const float NL2E = -5.770780163555852f;   // -4 * log2(e)
        #pragma unroll
        for (int ii = 0; ii < 4; ii++) {
            int i0 = quad * 8 + 2 * ii;
            float d0 = rad - (float)i0 * step;
            float d1 = rad - (float)(i0 + 1) * step;
            A0.d[ii] = (unsigned)f2bf(__builtin_amdgcn_exp2f(d0 * d0 * NL2E))
                     | ((unsigned)f2bf(__builtin_amdgcn_exp2f(d1 * d1 * NL2E)) << 16);
            int i2 = 32 + i0;
            float e0 = rad - (float)i2 * step;
            float e1 = rad - (float)(i2 + 1) * step;
            A1.d[ii] = (unsigned)f2bf(__builtin_amdgcn_exp2f(e0 * e0 * NL2E))
                     | ((unsigned)f2bf(__builtin_amdgcn_exp2f(e1 * e1 * NL2E)) << 16);
        }
    }

    // ---- Phase B (wave-local): H = relu(B @ W1 + b1) -> Hw ----
    #pragma unroll
    for (int nt = 0; nt < 4; nt++) {
        bf16x8 bb0 = *(const bf16x8*)&g_w1s[((0 * 4 + nt) * 64 + lane) * 8];
        bf16x8 bb1 = *(const bf16x8*)&g_w1s[((1 * 4 + nt) * 64 + lane) * 8];
        f32x4 acc = {0.f, 0.f, 0.f, 0.f};
        acc = __builtin_amdgcn_mfma_f32_16x16x32_bf16(A0.v, bb0, acc, 0, 0, 0);
        acc = __builtin_amdgcn_mfma_f32_16x16x32_bf16(A1.v, bb1, acc, 0, 0, 0);
        int h = nt * 16 + l16;
        float bias = b1[h];
        #pragma unroll
        for (int rr = 0; rr < 4; rr++) {
            float v = acc[rr] + bias;
            v = v > 0.0f ? v : 0.0f;
            W.Hw[quad * 4 + rr][h] = f2bf(v);     // H[z = quad*4+rr][h]
        }
    }
    // Wave-internal LDS visibility (fence discipline proven in round 5).
    asm volatile("s_waitcnt lgkmcnt(0)" ::: "memory");
    __builtin_amdgcn_sched_barrier(0);

    // ---- Phase C (wave-local): R = H @ W2 + b2 -> Rw ----
    {
        bf16x8 h0 = *(const bf16x8*)&W.Hw[l16][0 + quad * 8];
        bf16x8 h1 = *(const bf16x8*)&W.Hw[l16][32 + quad * 8];
        #pragma unroll
        for (int nt = 0; nt < 4; nt++) {
            bf16x8 bb0 = *(const bf16x8*)&g_w2s[((0 * 4 + nt) * 64 + lane) * 8];
            bf16x8 bb1 = *(const bf16x8*)&g_w2s[((1 * 4 + nt) * 64 + lane) * 8];
            f32x4 acc = {0.f, 0.f, 0.f, 0.f};
            acc = __builtin_amdgcn_mfma_f32_16x16x32_bf16(h0, bb0, acc, 0, 0, 0);
            acc = __builtin_amdgcn_mfma_f32_16x16x32_bf16(h1, bb1, acc, 0, 0, 0);
            int p = nt * 16 + l16;
            if (p < NPATH) {
                float bias = b2[p];
                #pragma unroll
                for (int rr = 0; rr < 4; rr++)
                    W.Rw[quad * 4 + rr][p] = f2bf(acc[rr] + bias);
            }
        }
    }
    asm volatile("s_waitcnt lgkmcnt(0)" ::: "memory");
    __builtin_amdgcn_sched_barrier(0);

    // ---- Phase D (in registers): az[kc] = coeff A-fragments for z = l16 ----
    // Element (kc, dword ii) covers k0 = kc*32 + quad*8 + 2*ii and k0+1;
    // pair index j = kc*16 + quad*4 + ii in [0,112). g_pyk zero-pads j >= 102,
    // so k >= KDIM gives finite garbage that multiplies zero-padded cg -> 0.
    frag az[7];
    #pragma unroll
    for (int kc = 0; kc < 7; kc++) {
        #pragma unroll
        for (int ii = 0; ii < 4; ii++) {
            unsigned py = g_pyk[kc * 16 + quad * 4 + ii];
            float cA = bf2f(W.Rw[l16][py & 255])         * W.Yw[l16][(py >> 8) & 255];
            float cB = bf2f(W.Rw[l16][(py >> 16) & 255]) * W.Yw[l16][py >> 24];
            az[kc].d[ii] = (unsigned)f2bf(cA) | ((unsigned)f2bf(cB) << 16);
        }
    }

    // ---- Phase E (wave-independent): own 16 z-rows x ALL 21 n-tiles ----
    // out row = z0 + wv*16 + quad*4 + rr, col = nt*16 + l16 (proven mapping).
    const int obase = (z0 + wv * 16 + quad * 4) * NIJ + l16;
    #pragma unroll 3
    for (int nt = 0; nt < NTIL; nt++) {
        f32x4 acc = {0.f, 0.f, 0.f, 0.f};
        #pragma unroll
        for (int kc = 0; kc < 7; kc++) {
            bf16x8 bg = *(const bf16x8*)&g_cgs[((kc * NTIL + nt) * 64 + lane) * 8];
            acc = __builtin_amdgcn_mfma_f32_16x16x32_bf16(az[kc].v, bg, acc, 0, 0, 0);
        }
        int col = nt * 16 + l16;
        if (col < NIJ) {                     // last tile covers cols 320..335
            #pragma unroll
            for (int rr = 0; rr < 4; rr++)
                out[obase + rr * NIJ + nt * 16] = acc[rr];
        }
    }
}

extern "C" void kernel_launch(void* const* d_in, const int* in_sizes, int n_in,
                              void* d_out, int out_size, void* d_ws, size_t ws_size,
                              hipStream_t stream) {
    const float* r   = (const float*)d_in[0];
    const float* W1  = (const float*)d_in[1];
    const float* b1  = (const float*)d_in[2];
    const float* W2  = (const float*)d_in[3];
    const float* b2  = (const float*)d_in[4];
    const float* cg  = (const float*)d_in[5];
    const float* rf  = (const float*)d_in[6];
    const float* ylm = (const float*)d_in[7];
    float* out = (float*)d_out;

    const int Z = in_sizes[0] / 3;

    prep_kernel<<<327, 256, 0, stream>>>(W1, W2, cg, rf, ylm);
    fused_kernel<<<Z / 64, 256, 0, stream>>>(r, b1, b2, out);
}